// Round 1
// baseline (1041.473 us; speedup 1.0000x reference)
//
#include <hip/hip_runtime.h>
#include <math.h>

// Pipeline (all fp32):
//  1) CSR build: hist(deg) -> block scan -> scan bsums -> finish(offs,cursor) -> scatter(perm_src, perm_ea)
//  2) k_aggr_h: per-dst-node softmax-aggregate (no max-subtraction; scores bounded) + residual -> h [N,128]
//  3) k_gemm_nt<true>: h1 = h @ W1^T [N,256], accumulate per-column sum/sumsq for BatchNorm
//  4) k_bn_finish: bnscale/bnshift from batch stats
//  5) k_gemm2: out_x = ELU(LN(relu(bn(h1)) @ W2^T)) -> d_out[0 .. N*128)
//  6) k_packM: M[j,d] = We[j,d] (j<128) else We[j-128,128+d]
//  7) k_gemm_nt<false>: C_AB = out_x @ M^T [N,256]  (per-node halves of the edge MLP)
//  8) k_edge_out: out_e[i] = LN(gelu(C_AB[src,:128] + C_AB[dst,128:] + be)) -> d_out[N*128 ..)
//
// Workspace (~77 MB): h (N*128 f32), C (N*256 f32, reused: h1 then C_AB; CSR arrays aliased
// into C before it is first written), small stats region + packed M.

#define DIVUP(a, b) (((a) + (b) - 1) / (b))

// ---------------- CSR build ----------------

__global__ __launch_bounds__(256) void k_hist(const int* __restrict__ dst, int* __restrict__ deg, int E) {
    int i = blockIdx.x * 256 + threadIdx.x;
    if (i < E) atomicAdd(&deg[dst[i]], 1);
}

__global__ __launch_bounds__(256) void k_scan_block(const int* __restrict__ deg, int* __restrict__ tmp,
                                                    int* __restrict__ bsum, int n) {
    __shared__ int sh[256];
    int i = blockIdx.x * 256 + threadIdx.x;
    int v = (i < n) ? deg[i] : 0;
    sh[threadIdx.x] = v;
    __syncthreads();
    #pragma unroll
    for (int off = 1; off < 256; off <<= 1) {
        int t = (threadIdx.x >= off) ? sh[threadIdx.x - off] : 0;
        __syncthreads();
        sh[threadIdx.x] += t;
        __syncthreads();
    }
    if (i < n) tmp[i] = sh[threadIdx.x];
    if (threadIdx.x == 255) bsum[blockIdx.x] = sh[255];
}

__global__ __launch_bounds__(256) void k_scan_bsum(const int* __restrict__ bsum, int* __restrict__ bsum_ex, int nb) {
    __shared__ int sh[256];
    int t = threadIdx.x;
    int v = (t < nb) ? bsum[t] : 0;
    sh[t] = v;
    __syncthreads();
    #pragma unroll
    for (int off = 1; off < 256; off <<= 1) {
        int u = (t >= off) ? sh[t - off] : 0;
        __syncthreads();
        sh[t] += u;
        __syncthreads();
    }
    bsum_ex[t] = sh[t] - v;  // exclusive
}

__global__ __launch_bounds__(256) void k_scan_finish(const int* __restrict__ tmp, const int* __restrict__ deg,
                                                     const int* __restrict__ bsum_ex, int* __restrict__ offs,
                                                     int* __restrict__ cursor, int n) {
    int i = blockIdx.x * 256 + threadIdx.x;
    if (i < n) {
        int ex = tmp[i] - deg[i] + bsum_ex[blockIdx.x];
        offs[i] = ex;
        cursor[i] = ex;
    }
}

__global__ __launch_bounds__(256) void k_scatter(const int* __restrict__ src, const int* __restrict__ dst,
                                                 const float* __restrict__ ea, int* __restrict__ cursor,
                                                 int* __restrict__ perm_src, float* __restrict__ perm_ea, int E) {
    int i = blockIdx.x * 256 + threadIdx.x;
    if (i < E) {
        int d = dst[i];
        int pos = atomicAdd(&cursor[d], 1);
        perm_src[pos] = src[i];
        perm_ea[pos] = ea[i];
    }
}

// ---------------- softmax-aggregate + residual ----------------
// One block (128 threads) per destination node; channel = threadIdx.x.
// No max-subtraction: scores = msg*t bounded (~<=9 for this data), exp fits fp32 easily.
__global__ __launch_bounds__(128) void k_aggr_h(const int* __restrict__ offs, const int* __restrict__ deg,
                                                const int* __restrict__ perm_src, const float* __restrict__ perm_ea,
                                                const float* __restrict__ x, const float* __restrict__ W_edge,
                                                const float* __restrict__ t_ptr, float* __restrict__ h, int n) {
    int node = blockIdx.x;
    int d = threadIdx.x;
    float t = *t_ptr;
    float we = W_edge[d];
    int start = offs[node], cnt = deg[node];
    float denom = 0.f, numer = 0.f;
    for (int e = 0; e < cnt; ++e) {
        int s = perm_src[start + e];
        float ea = perm_ea[start + e];
        float m = fmaxf(x[(size_t)s * 128 + d] + ea * we, 0.f) + 1e-7f;
        float es = __expf(m * t);
        denom += es;
        numer += m * es;
    }
    h[(size_t)node * 128 + d] = numer / (denom + 1e-16f) + x[(size_t)node * 128 + d];
}

// ---------------- GEMM: C[n,j] = sum_k A[n,k]*B[j,k], K=128, 256 cols ----------------
// 64x64 tile per block, K-chunks of 64. Micro-tile: rows ty*4+i, cols j*16+tx (stride-16
// cols keep all LDS frag reads <=2-way bank conflicts = free). Optional BN column stats.
template <bool STATS>
__global__ __launch_bounds__(256) void k_gemm_nt(const float* __restrict__ A, const float* __restrict__ B,
                                                 float* __restrict__ C, int nrows,
                                                 float* __restrict__ colsum, float* __restrict__ colsq) {
    __shared__ float As[64 * 68];
    __shared__ float Bs[64 * 68];
    const int row0 = blockIdx.x * 64, col0 = blockIdx.y * 64;
    const int tid = threadIdx.x;
    const int tx = tid & 15, ty = tid >> 4;
    float acc[4][4] = {};
    for (int kc = 0; kc < 128; kc += 64) {
        #pragma unroll
        for (int q = 0; q < 4; q++) {
            int f = tid + q * 256;
            int r = f >> 4, c4 = f & 15;
            int gr = row0 + r;
            float4 av = (gr < nrows) ? *(const float4*)(A + (size_t)gr * 128 + kc + c4 * 4)
                                     : make_float4(0.f, 0.f, 0.f, 0.f);
            *(float4*)(As + r * 68 + c4 * 4) = av;
            float4 bv = *(const float4*)(B + (size_t)(col0 + r) * 128 + kc + c4 * 4);
            *(float4*)(Bs + r * 68 + c4 * 4) = bv;
        }
        __syncthreads();
        #pragma unroll
        for (int k0 = 0; k0 < 64; k0 += 4) {
            float4 a4[4], b4[4];
            #pragma unroll
            for (int i = 0; i < 4; i++) a4[i] = *(const float4*)(As + (ty * 4 + i) * 68 + k0);
            #pragma unroll
            for (int j = 0; j < 4; j++) b4[j] = *(const float4*)(Bs + (j * 16 + tx) * 68 + k0);
            #pragma unroll
            for (int i = 0; i < 4; i++)
                #pragma unroll
                for (int j = 0; j < 4; j++) {
                    acc[i][j] = fmaf(a4[i].x, b4[j].x, acc[i][j]);
                    acc[i][j] = fmaf(a4[i].y, b4[j].y, acc[i][j]);
                    acc[i][j] = fmaf(a4[i].z, b4[j].z, acc[i][j]);
                    acc[i][j] = fmaf(a4[i].w, b4[j].w, acc[i][j]);
                }
        }
        __syncthreads();
    }
    #pragma unroll
    for (int i = 0; i < 4; i++) {
        int gr = row0 + ty * 4 + i;
        if (gr < nrows) {
            #pragma unroll
            for (int j = 0; j < 4; j++) C[(size_t)gr * 256 + col0 + j * 16 + tx] = acc[i][j];
        }
    }
    if (STATS) {
        // OOB rows were staged as zeros -> acc==0 -> contribute 0 to the stats. Correct.
        __syncthreads();
        float* redS = As;         // 64 cols x 16 ty
        float* redQ = As + 1024;  // 64 cols x 16 ty
        #pragma unroll
        for (int j = 0; j < 4; j++) {
            float s = 0.f, qq = 0.f;
            #pragma unroll
            for (int i = 0; i < 4; i++) {
                s += acc[i][j];
                qq += acc[i][j] * acc[i][j];
            }
            redS[(j * 16 + tx) * 16 + ty] = s;
            redQ[(j * 16 + tx) * 16 + ty] = qq;
        }
        __syncthreads();
        if (tid < 64) {
            float s = 0.f, qq = 0.f;
            #pragma unroll
            for (int u = 0; u < 16; u++) {
                s += redS[tid * 16 + u];
                qq += redQ[tid * 16 + u];
            }
            atomicAdd(&colsum[col0 + tid], s);
            atomicAdd(&colsq[col0 + tid], qq);
        }
    }
}

__global__ __launch_bounds__(256) void k_bn_finish(const float* __restrict__ colsum, const float* __restrict__ colsq,
                                                   const float* __restrict__ g, const float* __restrict__ b,
                                                   float* __restrict__ scale, float* __restrict__ shift, float invN) {
    int j = threadIdx.x;  // 256
    float mu = colsum[j] * invN;
    float var = colsq[j] * invN - mu * mu;
    float sc = g[j] * rsqrtf(var + 1e-5f);
    scale[j] = sc;
    shift[j] = b[j] - mu * sc;
}

// ---------------- GEMM2: out_x = ELU(LN(relu(bn(h1)) @ W2^T)) ----------------
// 64 rows x 128 cols per block, K=256 in chunks of 64. BN affine + relu fused into A-staging.
__global__ __launch_bounds__(256) void k_gemm2(const float* __restrict__ H1, const float* __restrict__ W2,
                                               const float* __restrict__ bnscale, const float* __restrict__ bnshift,
                                               const float* __restrict__ lng, const float* __restrict__ lnb,
                                               float* __restrict__ outx, int nrows) {
    __shared__ float As[64 * 68];
    __shared__ float Bs[128 * 68];
    __shared__ float redS[64 * 16];
    __shared__ float redQ[64 * 16];
    __shared__ float rmean[64], rrstd[64];
    const int row0 = blockIdx.x * 64;
    const int tid = threadIdx.x;
    const int tx = tid & 15, ty = tid >> 4;
    float acc[4][8] = {};
    for (int kc = 0; kc < 256; kc += 64) {
        #pragma unroll
        for (int q = 0; q < 4; q++) {
            int f = tid + q * 256;
            int r = f >> 4, c4 = f & 15;
            int gr = row0 + r, kg = kc + c4 * 4;
            float4 v = (gr < nrows) ? *(const float4*)(H1 + (size_t)gr * 256 + kg)
                                    : make_float4(0.f, 0.f, 0.f, 0.f);
            float4 sc = *(const float4*)(bnscale + kg);
            float4 sh = *(const float4*)(bnshift + kg);
            v.x = fmaxf(fmaf(v.x, sc.x, sh.x), 0.f);
            v.y = fmaxf(fmaf(v.y, sc.y, sh.y), 0.f);
            v.z = fmaxf(fmaf(v.z, sc.z, sh.z), 0.f);
            v.w = fmaxf(fmaf(v.w, sc.w, sh.w), 0.f);
            *(float4*)(As + r * 68 + c4 * 4) = v;
        }
        #pragma unroll
        for (int q = 0; q < 8; q++) {
            int f = tid + q * 256;
            int r = f >> 4, c4 = f & 15;
            float4 w = *(const float4*)(W2 + (size_t)r * 256 + kc + c4 * 4);
            *(float4*)(Bs + r * 68 + c4 * 4) = w;
        }
        __syncthreads();
        #pragma unroll
        for (int k0 = 0; k0 < 64; k0 += 4) {
            float4 a4[4], b4[8];
            #pragma unroll
            for (int i = 0; i < 4; i++) a4[i] = *(const float4*)(As + (ty * 4 + i) * 68 + k0);
            #pragma unroll
            for (int j = 0; j < 8; j++) b4[j] = *(const float4*)(Bs + (j * 16 + tx) * 68 + k0);
            #pragma unroll
            for (int i = 0; i < 4; i++)
                #pragma unroll
                for (int j = 0; j < 8; j++) {
                    acc[i][j] = fmaf(a4[i].x, b4[j].x, acc[i][j]);
                    acc[i][j] = fmaf(a4[i].y, b4[j].y, acc[i][j]);
                    acc[i][j] = fmaf(a4[i].z, b4[j].z, acc[i][j]);
                    acc[i][j] = fmaf(a4[i].w, b4[j].w, acc[i][j]);
                }
        }
        __syncthreads();
    }
    // Row LayerNorm (over 128 cols) + ELU epilogue
    #pragma unroll
    for (int i = 0; i < 4; i++) {
        float s = 0.f, qq = 0.f;
        #pragma unroll
        for (int j = 0; j < 8; j++) {
            s += acc[i][j];
            qq += acc[i][j] * acc[i][j];
        }
        redS[(ty * 4 + i) * 16 + tx] = s;
        redQ[(ty * 4 + i) * 16 + tx] = qq;
    }
    __syncthreads();
    if (tid < 64) {
        float s = 0.f, qq = 0.f;
        #pragma unroll
        for (int u = 0; u < 16; u++) {
            s += redS[tid * 16 + u];
            qq += redQ[tid * 16 + u];
        }
        float mu = s * (1.f / 128.f);
        float var = qq * (1.f / 128.f) - mu * mu;
        rmean[tid] = mu;
        rrstd[tid] = rsqrtf(var + 1e-5f);
    }
    __syncthreads();
    #pragma unroll
    for (int i = 0; i < 4; i++) {
        int lr = ty * 4 + i;
        int gr = row0 + lr;
        if (gr < nrows) {
            float mu = rmean[lr], rs = rrstd[lr];
            #pragma unroll
            for (int j = 0; j < 8; j++) {
                int col = j * 16 + tx;
                float v = (acc[i][j] - mu) * rs * lng[col] + lnb[col];
                v = v > 0.f ? v : expm1f(v);
                outx[(size_t)gr * 128 + col] = v;
            }
        }
    }
}

// ---------------- pack M for the edge-MLP factorization ----------------
__global__ __launch_bounds__(256) void k_packM(const float* __restrict__ We, float* __restrict__ M) {
    int i = blockIdx.x * 256 + threadIdx.x;  // 32768
    int j = i >> 7, d = i & 127;
    M[i] = (j < 128) ? We[j * 256 + d] : We[(j - 128) * 256 + 128 + d];
}

// ---------------- edge output: gather halves, GELU, wave LayerNorm ----------------
// One wave (64 lanes) per edge, 2 channels per lane; pure shuffle reduction.
__global__ __launch_bounds__(256) void k_edge_out(const int* __restrict__ src, const int* __restrict__ dst,
                                                  const float* __restrict__ CAB, const float* __restrict__ be,
                                                  const float* __restrict__ lng, const float* __restrict__ lnb,
                                                  float* __restrict__ oute, int E) {
    int e = blockIdx.x * 4 + (threadIdx.x >> 6);
    int lane = threadIdx.x & 63;
    if (e >= E) return;
    int s = src[e], d = dst[e];
    int k = lane * 2;
    float2 va = *(const float2*)(CAB + (size_t)s * 256 + k);
    float2 vb = *(const float2*)(CAB + (size_t)d * 256 + 128 + k);
    float2 bb = *(const float2*)(be + k);
    float x0 = va.x + vb.x + bb.x;
    float x1 = va.y + vb.y + bb.y;
    const float is2 = 0.70710678118654752f;
    float g0 = 0.5f * x0 * (1.f + erff(x0 * is2));
    float g1 = 0.5f * x1 * (1.f + erff(x1 * is2));
    float s1 = g0 + g1, s2 = g0 * g0 + g1 * g1;
    #pragma unroll
    for (int off = 32; off; off >>= 1) {
        s1 += __shfl_xor(s1, off);
        s2 += __shfl_xor(s2, off);
    }
    float mu = s1 * (1.f / 128.f);
    float var = s2 * (1.f / 128.f) - mu * mu;
    float rs = rsqrtf(var + 1e-5f);
    float2 gg = *(const float2*)(lng + k);
    float2 b2 = *(const float2*)(lnb + k);
    float o0 = (g0 - mu) * rs * gg.x + b2.x;
    float o1 = (g1 - mu) * rs * gg.y + b2.y;
    *(float2*)(oute + (size_t)e * 128 + k) = make_float2(o0, o1);
}

extern "C" void kernel_launch(void* const* d_in, const int* in_sizes, int n_in,
                              void* d_out, int out_size, void* d_ws, size_t ws_size,
                              hipStream_t stream) {
    const int N = in_sizes[0] / 128;  // 50000
    const int E = in_sizes[1] / 2;    // 800000

    const float* x      = (const float*)d_in[0];
    const int*   ei     = (const int*)d_in[1];
    const int*   src    = ei;
    const int*   dst    = ei + E;
    const float* ea     = (const float*)d_in[2];
    const float* W_edge = (const float*)d_in[3];
    const float* t_ptr  = (const float*)d_in[4];
    const float* W1     = (const float*)d_in[5];
    const float* bng    = (const float*)d_in[6];
    const float* bnb    = (const float*)d_in[7];
    const float* W2     = (const float*)d_in[8];
    const float* lng    = (const float*)d_in[9];
    const float* lnb    = (const float*)d_in[10];
    const float* We     = (const float*)d_in[11];
    const float* be     = (const float*)d_in[12];
    const float* lneg   = (const float*)d_in[13];
    const float* lneb   = (const float*)d_in[14];

    float* out_x = (float*)d_out;                      // [N,128]
    float* out_e = out_x + (size_t)N * 128;            // [E,128]

    // ---- workspace layout ----
    float* h = (float*)d_ws;                           // N*128
    float* C = h + (size_t)N * 128;                    // N*256 (h1, later C_AB)
    // CSR scratch aliased into C (dead before C is first written by GEMM1):
    int*   perm_src = (int*)C;                         // E
    float* perm_ea  = (float*)(perm_src + E);          // E
    int*   deg      = (int*)(perm_ea + E);             // N
    int*   offs     = deg + N;                         // N
    int*   cursor   = offs + N;                        // N
    int*   tmp      = cursor + N;                      // N
    int*   bsum     = tmp + N;                         // 256
    int*   bsum_ex  = bsum + 256;                      // 256
    // persistent small region after C:
    float* small    = C + (size_t)N * 256;
    float* colsum   = small;                           // 256
    float* colsq    = small + 256;                     // 256
    float* bnscale  = small + 512;                     // 256
    float* bnshift  = small + 768;                     // 256
    float* M        = small + 1024;                    // 256*128

    const int EB = DIVUP(E, 256);
    const int NB = DIVUP(N, 256);
    const int GR = DIVUP(N, 64);

    // zero accumulators (ws is poisoned 0xAA before every call)
    hipMemsetAsync(deg, 0, (size_t)N * sizeof(int), stream);
    hipMemsetAsync(colsum, 0, 512 * sizeof(float), stream);

    // CSR build
    k_hist<<<EB, 256, 0, stream>>>(dst, deg, E);
    k_scan_block<<<NB, 256, 0, stream>>>(deg, tmp, bsum, N);
    k_scan_bsum<<<1, 256, 0, stream>>>(bsum, bsum_ex, NB);
    k_scan_finish<<<NB, 256, 0, stream>>>(tmp, deg, bsum_ex, offs, cursor, N);
    k_scatter<<<EB, 256, 0, stream>>>(src, dst, ea, cursor, perm_src, perm_ea, E);

    // GENConv aggregate + residual
    k_aggr_h<<<N, 128, 0, stream>>>(offs, deg, perm_src, perm_ea, x, W_edge, t_ptr, h, N);

    // MLP
    k_gemm_nt<true><<<dim3(GR, 4), 256, 0, stream>>>(h, W1, C, N, colsum, colsq);
    k_bn_finish<<<1, 256, 0, stream>>>(colsum, colsq, bng, bnb, bnscale, bnshift, 1.0f / (float)N);
    k_gemm2<<<GR, 256, 0, stream>>>(C, W2, bnscale, bnshift, lng, lnb, out_x, N);

    // edge MLP (factorized per-node)
    k_packM<<<128, 256, 0, stream>>>(We, M);
    k_gemm_nt<false><<<dim3(GR, 4), 256, 0, stream>>>(out_x, M, C, N, nullptr, nullptr);
    k_edge_out<<<DIVUP(E, 4), 256, 0, stream>>>(src, dst, C, be, lneg, lneb, out_e, E);
}

// Round 2
// 909.453 us; speedup vs baseline: 1.1452x; 1.1452x over previous
//
#include <hip/hip_runtime.h>
#include <math.h>

typedef _Float16 f16;
typedef _Float16 f16x4 __attribute__((ext_vector_type(4)));
typedef _Float16 f16x8 __attribute__((ext_vector_type(8)));
typedef float f32x4 __attribute__((ext_vector_type(4)));

#define DIVUP(a, b) (((a) + (b) - 1) / (b))

// ---------------- CSR build ----------------

__global__ __launch_bounds__(256) void k_hist(const int* __restrict__ dst, int* __restrict__ deg, int E) {
    int i = blockIdx.x * 256 + threadIdx.x;
    if (i < E) atomicAdd(&deg[dst[i]], 1);
}

__global__ __launch_bounds__(256) void k_scan_block(const int* __restrict__ deg, int* __restrict__ tmp,
                                                    int* __restrict__ bsum, int n) {
    __shared__ int sh[256];
    int i = blockIdx.x * 256 + threadIdx.x;
    int v = (i < n) ? deg[i] : 0;
    sh[threadIdx.x] = v;
    __syncthreads();
    #pragma unroll
    for (int off = 1; off < 256; off <<= 1) {
        int t = (threadIdx.x >= off) ? sh[threadIdx.x - off] : 0;
        __syncthreads();
        sh[threadIdx.x] += t;
        __syncthreads();
    }
    if (i < n) tmp[i] = sh[threadIdx.x];
    if (threadIdx.x == 255) bsum[blockIdx.x] = sh[255];
}

__global__ __launch_bounds__(256) void k_scan_bsum(const int* __restrict__ bsum, int* __restrict__ bsum_ex, int nb) {
    __shared__ int sh[256];
    int t = threadIdx.x;
    int v = (t < nb) ? bsum[t] : 0;
    sh[t] = v;
    __syncthreads();
    #pragma unroll
    for (int off = 1; off < 256; off <<= 1) {
        int u = (t >= off) ? sh[t - off] : 0;
        __syncthreads();
        sh[t] += u;
        __syncthreads();
    }
    bsum_ex[t] = sh[t] - v;  // exclusive
}

__global__ __launch_bounds__(256) void k_scan_finish(const int* __restrict__ tmp, const int* __restrict__ deg,
                                                     const int* __restrict__ bsum_ex, int* __restrict__ offs,
                                                     int* __restrict__ cursor, int n) {
    int i = blockIdx.x * 256 + threadIdx.x;
    if (i < n) {
        int ex = tmp[i] - deg[i] + bsum_ex[blockIdx.x];
        offs[i] = ex;
        cursor[i] = ex;
    }
}

__global__ __launch_bounds__(256) void k_scatter(const int* __restrict__ src, const int* __restrict__ dst,
                                                 const float* __restrict__ ea, int* __restrict__ cursor,
                                                 int2* __restrict__ perm, int E) {
    int i = blockIdx.x * 256 + threadIdx.x;
    if (i < E) {
        int d = dst[i];
        int pos = atomicAdd(&cursor[d], 1);
        perm[pos] = make_int2(src[i], __float_as_int(ea[i]));
    }
}

// ---------------- softmax-aggregate + residual ----------------
__global__ __launch_bounds__(128) void k_aggr_h(const int* __restrict__ offs, const int* __restrict__ deg,
                                                const int2* __restrict__ perm,
                                                const float* __restrict__ x, const float* __restrict__ W_edge,
                                                const float* __restrict__ t_ptr, float* __restrict__ h, int n) {
    int node = blockIdx.x;
    int d = threadIdx.x;
    float t = *t_ptr;
    float we = W_edge[d];
    int start = offs[node], cnt = deg[node];
    float denom = 0.f, numer = 0.f;
    for (int e = 0; e < cnt; ++e) {
        int2 pe = perm[start + e];
        int s = pe.x;
        float ea = __int_as_float(pe.y);
        float m = fmaxf(x[(size_t)s * 128 + d] + ea * we, 0.f) + 1e-7f;
        float es = __expf(m * t);
        denom += es;
        numer += m * es;
    }
    h[(size_t)node * 128 + d] = numer / (denom + 1e-16f) + x[(size_t)node * 128 + d];
}

// ---------------- weight prep: fp32 -> f16 (and pack M for edge MLP) ----------------
__global__ __launch_bounds__(256) void k_prep(const float* __restrict__ W1, const float* __restrict__ W2,
                                              const float* __restrict__ We, f16* __restrict__ B1,
                                              f16* __restrict__ B2, f16* __restrict__ BM) {
    int i = blockIdx.x * 256 + threadIdx.x;  // 3*32768
    if (i < 32768) {
        B1[i] = (f16)W1[i];
    } else if (i < 65536) {
        int j = i - 32768;
        B2[j] = (f16)W2[j];
    } else {
        int j = i - 65536;
        int jj = j >> 7, d = j & 127;
        BM[j] = (f16)((jj < 128) ? We[jj * 256 + d] : We[(jj - 128) * 256 + 128 + d]);
    }
}

// ---------------- unified MFMA GEMM: C[n,j] = sum_k A[n,k]*B[j,k] ----------------
// A fp32 [nrows x KTOT] (lda==KTOT), Bg f16 [ncols x KTOT]. 128x128 tile per block,
// 4 waves of 64x64 via 16x16x32 f16 MFMA. LDS stride 136 (f16) keeps frag reads ~2-way.
// MODE 0: store C (stride 256) + BN column stats (atomics).
// MODE 1: BN affine+relu fused into A staging, row-LN+ELU epilogue, store (stride 128).
// MODE 2: plain store C (stride 256).
template <int KTOT, int MODE>
__global__ __launch_bounds__(256) void k_gemm(const float* __restrict__ A, const f16* __restrict__ Bg,
                                              float* __restrict__ Cout, int nrows,
                                              float* __restrict__ colsum, float* __restrict__ colsq,
                                              const float* __restrict__ bnscale, const float* __restrict__ bnshift,
                                              const float* __restrict__ lng, const float* __restrict__ lnb) {
    __shared__ f16 As[128 * 136];
    __shared__ f16 Bs[128 * 136];
    __shared__ float Ssum[2][128];
    __shared__ float Sq[2][128];
    const int tid = threadIdx.x;
    const int lane = tid & 63, w = tid >> 6;
    const int m = lane & 15, quad = lane >> 4;
    const int row0 = blockIdx.x * 128, col0 = blockIdx.y * 128;
    const int wrow = (w & 1) * 64, wcol = (w >> 1) * 64;
    f32x4 acc[4][4] = {};

    for (int kc = 0; kc < KTOT; kc += 128) {
        if (kc) __syncthreads();
        // stage A (fp32 -> f16), optional BN+relu
        #pragma unroll
        for (int q = 0; q < 16; q++) {
            int f = tid + q * 256;
            int r = f >> 5, c4 = f & 31;
            int gr = row0 + r;
            float4 v = (gr < nrows) ? *(const float4*)(A + (size_t)gr * KTOT + kc + c4 * 4)
                                    : make_float4(0.f, 0.f, 0.f, 0.f);
            if (MODE == 1) {
                float4 sc = *(const float4*)(bnscale + kc + c4 * 4);
                float4 sh = *(const float4*)(bnshift + kc + c4 * 4);
                v.x = fmaxf(fmaf(v.x, sc.x, sh.x), 0.f);
                v.y = fmaxf(fmaf(v.y, sc.y, sh.y), 0.f);
                v.z = fmaxf(fmaf(v.z, sc.z, sh.z), 0.f);
                v.w = fmaxf(fmaf(v.w, sc.w, sh.w), 0.f);
            }
            f16x4 hv = {(f16)v.x, (f16)v.y, (f16)v.z, (f16)v.w};
            *(f16x4*)(As + r * 136 + c4 * 4) = hv;
        }
        // stage B (already f16)
        #pragma unroll
        for (int q = 0; q < 8; q++) {
            int f = tid + q * 256;
            int r = f >> 4, k8 = f & 15;
            *(uint4*)(Bs + r * 136 + k8 * 8) =
                *(const uint4*)(Bg + (size_t)(col0 + r) * KTOT + kc + k8 * 8);
        }
        __syncthreads();
        #pragma unroll
        for (int k0 = 0; k0 < 128; k0 += 32) {
            f16x8 a[4], b[4];
            #pragma unroll
            for (int i = 0; i < 4; i++)
                a[i] = *(const f16x8*)(As + (wrow + i * 16 + m) * 136 + k0 + quad * 8);
            #pragma unroll
            for (int j = 0; j < 4; j++)
                b[j] = *(const f16x8*)(Bs + (wcol + j * 16 + m) * 136 + k0 + quad * 8);
            #pragma unroll
            for (int i = 0; i < 4; i++)
                #pragma unroll
                for (int j = 0; j < 4; j++)
                    acc[i][j] = __builtin_amdgcn_mfma_f32_16x16x32_f16(a[i], b[j], acc[i][j], 0, 0, 0);
        }
    }

    if (MODE == 0 || MODE == 2) {
        #pragma unroll
        for (int i = 0; i < 4; i++)
            #pragma unroll
            for (int r = 0; r < 4; r++) {
                int grow = row0 + wrow + i * 16 + quad * 4 + r;
                if (grow < nrows) {
                    #pragma unroll
                    for (int j = 0; j < 4; j++)
                        Cout[(size_t)grow * 256 + col0 + wcol + j * 16 + m] = acc[i][j][r];
                }
            }
    }
    if (MODE == 0) {
        // BN column stats: per-lane partial over its 16 rows, xor-16/32 reduce across quads,
        // lanes 0..15 hold 64-row totals for this wave -> global atomics.
        #pragma unroll
        for (int j = 0; j < 4; j++) {
            float s = 0.f, qq = 0.f;
            #pragma unroll
            for (int i = 0; i < 4; i++)
                #pragma unroll
                for (int r = 0; r < 4; r++) {
                    float v = acc[i][j][r];
                    s += v;
                    qq += v * v;
                }
            s += __shfl_xor(s, 16); s += __shfl_xor(s, 32);
            qq += __shfl_xor(qq, 16); qq += __shfl_xor(qq, 32);
            if (lane < 16) {
                atomicAdd(&colsum[col0 + wcol + j * 16 + lane], s);
                atomicAdd(&colsq[col0 + wcol + j * 16 + lane], qq);
            }
        }
    }
    if (MODE == 1) {
        // row-LN over 128 cols + ELU. xor 1/2/4/8 reduce within quads (64 cols per wave),
        // cross-col-wave combine via tiny LDS arrays.
        const int cw = w >> 1;
        #pragma unroll
        for (int i = 0; i < 4; i++)
            #pragma unroll
            for (int r = 0; r < 4; r++) {
                float s = 0.f, qq = 0.f;
                #pragma unroll
                for (int j = 0; j < 4; j++) {
                    float v = acc[i][j][r];
                    s += v;
                    qq += v * v;
                }
                s += __shfl_xor(s, 1); s += __shfl_xor(s, 2);
                s += __shfl_xor(s, 4); s += __shfl_xor(s, 8);
                qq += __shfl_xor(qq, 1); qq += __shfl_xor(qq, 2);
                qq += __shfl_xor(qq, 4); qq += __shfl_xor(qq, 8);
                if (m == 0) {
                    int lrow = wrow + i * 16 + quad * 4 + r;
                    Ssum[cw][lrow] = s;
                    Sq[cw][lrow] = qq;
                }
            }
        __syncthreads();
        float lg[4], lb[4];
        #pragma unroll
        for (int j = 0; j < 4; j++) {
            lg[j] = lng[wcol + j * 16 + m];
            lb[j] = lnb[wcol + j * 16 + m];
        }
        #pragma unroll
        for (int i = 0; i < 4; i++)
            #pragma unroll
            for (int r = 0; r < 4; r++) {
                int lrow = wrow + i * 16 + quad * 4 + r;
                int grow = row0 + lrow;
                if (grow < nrows) {
                    float S = Ssum[0][lrow] + Ssum[1][lrow];
                    float Q = Sq[0][lrow] + Sq[1][lrow];
                    float mu = S * (1.f / 128.f);
                    float var = Q * (1.f / 128.f) - mu * mu;
                    float rs = rsqrtf(var + 1e-5f);
                    #pragma unroll
                    for (int j = 0; j < 4; j++) {
                        float v = (acc[i][j][r] - mu) * rs * lg[j] + lb[j];
                        v = v > 0.f ? v : expm1f(v);
                        Cout[(size_t)grow * 128 + wcol + j * 16 + m] = v;
                    }
                }
            }
    }
}

__global__ __launch_bounds__(256) void k_bn_finish(const float* __restrict__ colsum, const float* __restrict__ colsq,
                                                   const float* __restrict__ g, const float* __restrict__ b,
                                                   float* __restrict__ scale, float* __restrict__ shift, float invN) {
    int j = threadIdx.x;  // 256
    float mu = colsum[j] * invN;
    float var = colsq[j] * invN - mu * mu;
    float sc = g[j] * rsqrtf(var + 1e-5f);
    scale[j] = sc;
    shift[j] = b[j] - mu * sc;
}

// ---------------- edge output: gather halves, GELU, wave LayerNorm ----------------
__global__ __launch_bounds__(256) void k_edge_out(const int* __restrict__ src, const int* __restrict__ dst,
                                                  const float* __restrict__ CAB, const float* __restrict__ be,
                                                  const float* __restrict__ lng, const float* __restrict__ lnb,
                                                  float* __restrict__ oute, int E) {
    int e = blockIdx.x * 4 + (threadIdx.x >> 6);
    int lane = threadIdx.x & 63;
    if (e >= E) return;
    int s = src[e], d = dst[e];
    int k = lane * 2;
    float2 va = *(const float2*)(CAB + (size_t)s * 256 + k);
    float2 vb = *(const float2*)(CAB + (size_t)d * 256 + 128 + k);
    float2 bb = *(const float2*)(be + k);
    float x0 = va.x + vb.x + bb.x;
    float x1 = va.y + vb.y + bb.y;
    const float is2 = 0.70710678118654752f;
    float g0 = 0.5f * x0 * (1.f + erff(x0 * is2));
    float g1 = 0.5f * x1 * (1.f + erff(x1 * is2));
    float s1 = g0 + g1, s2 = g0 * g0 + g1 * g1;
    #pragma unroll
    for (int off = 32; off; off >>= 1) {
        s1 += __shfl_xor(s1, off);
        s2 += __shfl_xor(s2, off);
    }
    float mu = s1 * (1.f / 128.f);
    float var = s2 * (1.f / 128.f) - mu * mu;
    float rs = rsqrtf(var + 1e-5f);
    float2 gg = *(const float2*)(lng + k);
    float2 b2 = *(const float2*)(lnb + k);
    float o0 = (g0 - mu) * rs * gg.x + b2.x;
    float o1 = (g1 - mu) * rs * gg.y + b2.y;
    *(float2*)(oute + (size_t)e * 128 + k) = make_float2(o0, o1);
}

extern "C" void kernel_launch(void* const* d_in, const int* in_sizes, int n_in,
                              void* d_out, int out_size, void* d_ws, size_t ws_size,
                              hipStream_t stream) {
    const int N = in_sizes[0] / 128;  // 50000
    const int E = in_sizes[1] / 2;    // 800000

    const float* x      = (const float*)d_in[0];
    const int*   ei     = (const int*)d_in[1];
    const int*   src    = ei;
    const int*   dst    = ei + E;
    const float* ea     = (const float*)d_in[2];
    const float* W_edge = (const float*)d_in[3];
    const float* t_ptr  = (const float*)d_in[4];
    const float* W1     = (const float*)d_in[5];
    const float* bng    = (const float*)d_in[6];
    const float* bnb    = (const float*)d_in[7];
    const float* W2     = (const float*)d_in[8];
    const float* lng    = (const float*)d_in[9];
    const float* lnb    = (const float*)d_in[10];
    const float* We     = (const float*)d_in[11];
    const float* be     = (const float*)d_in[12];
    const float* lneg   = (const float*)d_in[13];
    const float* lneb   = (const float*)d_in[14];

    float* out_x = (float*)d_out;                      // [N,128]
    float* out_e = out_x + (size_t)N * 128;            // [E,128]

    // ---- workspace layout ----
    float* h = (float*)d_ws;                           // N*128
    float* C = h + (size_t)N * 128;                    // N*256 (h1, later C_AB)
    // CSR scratch aliased into C (dead before GEMM1 writes C):
    int2*  perm     = (int2*)C;                        // E (src, ea-bits)
    int*   deg      = (int*)(perm + E);                // N
    int*   offs     = deg + N;                         // N
    int*   cursor   = offs + N;                        // N
    int*   tmp      = cursor + N;                      // N
    int*   bsum     = tmp + N;                         // 256
    int*   bsum_ex  = bsum + 256;                      // 256
    // persistent small region after C:
    float* small    = C + (size_t)N * 256;
    float* colsum   = small;                           // 256
    float* colsq    = small + 256;                     // 256
    float* bnscale  = small + 512;                     // 256
    float* bnshift  = small + 768;                     // 256
    f16*   B1f16    = (f16*)(small + 1024);            // 256*128
    f16*   B2f16    = B1f16 + 32768;                   // 128*256
    f16*   BMf16    = B2f16 + 32768;                   // 256*128

    const int EB = DIVUP(E, 256);
    const int NB = DIVUP(N, 256);
    const int GR = DIVUP(N, 128);

    hipMemsetAsync(deg, 0, (size_t)N * sizeof(int), stream);
    hipMemsetAsync(colsum, 0, 512 * sizeof(float), stream);

    // weight prep (independent of graph work)
    k_prep<<<384, 256, 0, stream>>>(W1, W2, We, B1f16, B2f16, BMf16);

    // CSR build
    k_hist<<<EB, 256, 0, stream>>>(dst, deg, E);
    k_scan_block<<<NB, 256, 0, stream>>>(deg, tmp, bsum, N);
    k_scan_bsum<<<1, 256, 0, stream>>>(bsum, bsum_ex, NB);
    k_scan_finish<<<NB, 256, 0, stream>>>(tmp, deg, bsum_ex, offs, cursor, N);
    k_scatter<<<EB, 256, 0, stream>>>(src, dst, ea, cursor, perm, E);

    // GENConv aggregate + residual
    k_aggr_h<<<N, 128, 0, stream>>>(offs, deg, perm, x, W_edge, t_ptr, h, N);

    // MLP (f16 MFMA)
    k_gemm<128, 0><<<dim3(GR, 2), 256, 0, stream>>>(h, B1f16, C, N, colsum, colsq,
                                                    nullptr, nullptr, nullptr, nullptr);
    k_bn_finish<<<1, 256, 0, stream>>>(colsum, colsq, bng, bnb, bnscale, bnshift, 1.0f / (float)N);
    k_gemm<256, 1><<<dim3(GR, 1), 256, 0, stream>>>(C, B2f16, out_x, N, nullptr, nullptr,
                                                    bnscale, bnshift, lng, lnb);

    // edge MLP (factorized per-node)
    k_gemm<128, 2><<<dim3(GR, 2), 256, 0, stream>>>(out_x, BMf16, C, N, nullptr, nullptr,
                                                    nullptr, nullptr, nullptr, nullptr);
    k_edge_out<<<DIVUP(E, 4), 256, 0, stream>>>(src, dst, C, be, lneg, lneb, out_e, E);
}